// Round 8
// baseline (31.686 us; speedup 1.0000x reference)
//
#include <hip/hip_runtime.h>

#define D_FEAT 128

// K1: per-node projection, 8-lane group per node (32 nodes / 256-thread block).
// pu[n] = h[n].Wu + b ; pv[n] = h[n].Wv
__global__ __launch_bounds__(256) void proj_kernel(
    const float* __restrict__ h,
    const float* __restrict__ W,
    const float* __restrict__ bptr,
    float* __restrict__ pu,
    float* __restrict__ pv,
    int n_nodes)
{
    const int t    = threadIdx.x & 7;
    const int node = blockIdx.x * 32 + (threadIdx.x >> 3);
    if (node >= n_nodes) return;

    const float4* W4 = (const float4*)W;
    float4 wu[4], wv[4];
    #pragma unroll
    for (int j = 0; j < 4; ++j) {
        wu[j] = W4[j * 8 + t];          // L1-resident after first wave
        wv[j] = W4[32 + j * 8 + t];
    }

    const float4* h4 = (const float4*)(h + (size_t)node * D_FEAT);
    float4 hv[4];
    #pragma unroll
    for (int j = 0; j < 4; ++j) hv[j] = h4[j * 8 + t];   // 64 B/lane in flight

    float su = 0.f, sv = 0.f;
    #pragma unroll
    for (int j = 0; j < 4; ++j) {
        su += hv[j].x*wu[j].x + hv[j].y*wu[j].y + hv[j].z*wu[j].z + hv[j].w*wu[j].w;
        sv += hv[j].x*wv[j].x + hv[j].y*wv[j].y + hv[j].z*wv[j].z + hv[j].w*wv[j].w;
    }
    #pragma unroll
    for (int off = 4; off > 0; off >>= 1) {   // xor 4,2,1: stays in 8-lane group
        su += __shfl_xor(su, off, 64);
        sv += __shfl_xor(sv, off, 64);
    }
    if (t == 0) {
        pu[node] = su + bptr[0];   // bias folded in: score = pu[src]+pv[dst]
        pv[node] = sv;
    }
}

// K2: 1 edge/thread, 3125 blocks (max TLP). Raw score -> out.
// Per-WAVE min/max partials to distinct addresses — no LDS reduce, no
// __syncthreads, no atomics. 12500 partial pairs total.
__global__ __launch_bounds__(256) void score_kernel(
    const int*   __restrict__ src,
    const int*   __restrict__ dst,
    const float* __restrict__ pu,
    const float* __restrict__ pv,
    float*       __restrict__ out,
    float*       __restrict__ pmin,
    float*       __restrict__ pmax,
    int n_edges)
{
    const int i = blockIdx.x * blockDim.x + threadIdx.x;
    float vmin =  3.4028235e38f;
    float vmax = -3.4028235e38f;
    if (i < n_edges) {
        const float s = pu[src[i]] + pv[dst[i]];   // pu/pv: 800 KB, L2-resident
        out[i] = s;
        vmin = s;
        vmax = s;
    }
    #pragma unroll
    for (int off = 32; off > 0; off >>= 1) {
        vmin = fminf(vmin, __shfl_xor(vmin, off, 64));
        vmax = fmaxf(vmax, __shfl_xor(vmax, off, 64));
    }
    if ((threadIdx.x & 63) == 0) {
        const int wid = blockIdx.x * 4 + (threadIdx.x >> 6);
        pmin[wid] = vmin;
        pmax[wid] = vmax;
    }
}

// K3: one 1024-thread block reduces the 12500 partial pairs -> g[0]=min, g[1]=max.
__global__ __launch_bounds__(1024) void minmax_reduce_kernel(
    const float* __restrict__ pmin,
    const float* __restrict__ pmax,
    float* __restrict__ g,
    int n)
{
    float vmin =  3.4028235e38f;
    float vmax = -3.4028235e38f;
    for (int i = threadIdx.x; i < n; i += 1024) {
        vmin = fminf(vmin, pmin[i]);
        vmax = fmaxf(vmax, pmax[i]);
    }
    #pragma unroll
    for (int off = 32; off > 0; off >>= 1) {
        vmin = fminf(vmin, __shfl_xor(vmin, off, 64));
        vmax = fmaxf(vmax, __shfl_xor(vmax, off, 64));
    }
    __shared__ float smin[16], smax[16];
    const int w = threadIdx.x >> 6;
    if ((threadIdx.x & 63) == 0) { smin[w] = vmin; smax[w] = vmax; }
    __syncthreads();
    if (threadIdx.x == 0) {
        float a = smin[0], m = smax[0];
        #pragma unroll
        for (int k = 1; k < 16; ++k) { a = fminf(a, smin[k]); m = fmaxf(m, smax[k]); }
        g[0] = a;
        g[1] = m;
    }
}

// K4: in-place normalize, float4, 1 vec4/thread (782 blocks).
__global__ __launch_bounds__(256) void norm_kernel(
    float* __restrict__ out,
    const float* __restrict__ g,
    int n4, int n_edges)
{
    const int i = blockIdx.x * blockDim.x + threadIdx.x;
    if (i >= n4) return;
    const float mn  = g[0];
    const float inv = 1.0f / (g[1] - mn);
    float4 v = ((const float4*)out)[i];
    v.x = (v.x - mn) * inv;
    v.y = (v.y - mn) * inv;
    v.z = (v.z - mn) * inv;
    v.w = (v.w - mn) * inv;
    ((float4*)out)[i] = v;
    if (i == n4 - 1) {
        for (int e = n4 * 4; e < n_edges; ++e)
            out[e] = (out[e] - mn) * inv;
    }
}

extern "C" void kernel_launch(void* const* d_in, const int* in_sizes, int n_in,
                              void* d_out, int out_size, void* d_ws, size_t ws_size,
                              hipStream_t stream) {
    const float* h   = (const float*)d_in[0];
    const int*   src = (const int*)d_in[1];
    const int*   dst = (const int*)d_in[2];
    const float* W   = (const float*)d_in[3];
    const float* b   = (const float*)d_in[4];
    float* out = (float*)d_out;

    const int n_nodes = in_sizes[0] / D_FEAT;
    const int n_edges = in_sizes[1];

    const int blk2   = (n_edges + 255) / 256;  // 3125
    const int nwaves = blk2 * 4;               // 12500 wave partials

    // workspace: pu[n_nodes], pv[n_nodes], pmin[nwaves], pmax[nwaves], g[2]
    float* ws   = (float*)d_ws;
    float* pu   = ws;
    float* pv   = ws + n_nodes;
    float* pmin = ws + 2 * n_nodes;
    float* pmax = pmin + nwaves;
    float* g    = pmax + nwaves;

    // K1: 32 nodes / block -> 3125 blocks
    {
        const int blocks = (n_nodes + 31) / 32;
        proj_kernel<<<blocks, 256, 0, stream>>>(h, W, b, pu, pv, n_nodes);
    }
    // K2: 1 edge/thread -> 3125 blocks, per-wave partials, no atomics
    score_kernel<<<blk2, 256, 0, stream>>>(src, dst, pu, pv, out, pmin, pmax, n_edges);
    // K3: single-block reduce of 12500 partials
    minmax_reduce_kernel<<<1, 1024, 0, stream>>>(pmin, pmax, g, nwaves);
    // K4: normalize in place
    {
        const int n4 = n_edges >> 2;           // 200000
        const int blocks = (n4 + 255) / 256;   // 782
        norm_kernel<<<blocks, 256, 0, stream>>>(out, g, n4, n_edges);
    }
}

// Round 9
// 29.268 us; speedup vs baseline: 1.0826x; 1.0826x over previous
//
#include <hip/hip_runtime.h>

#define D_FEAT 128

// K1: per-node projection; 2 nodes per 8-lane group (64 nodes / 256-thread block).
// pu[n] = h[n].Wu + b ; pv[n] = h[n].Wv
// Per thread: 8 W-fragment loads (amortized over 2 nodes) + 8 h loads
// (128 B/lane in flight); reduce = 3 shuffle rounds per accumulator.
__global__ __launch_bounds__(256) void proj_kernel(
    const float* __restrict__ h,
    const float* __restrict__ W,
    const float* __restrict__ bptr,
    float* __restrict__ pu,
    float* __restrict__ pv,
    int n_nodes)
{
    const int t     = threadIdx.x & 7;
    const int grp   = blockIdx.x * 32 + (threadIdx.x >> 3);   // 8-lane group id
    const int node0 = grp * 2;
    if (node0 >= n_nodes) return;

    const float4* W4 = (const float4*)W;
    float4 wu[4], wv[4];
    #pragma unroll
    for (int j = 0; j < 4; ++j) {
        wu[j] = W4[j * 8 + t];          // L1-resident after first wave
        wv[j] = W4[32 + j * 8 + t];
    }

    const bool two = (node0 + 1 < n_nodes);

    // issue all h loads first: up to 8 independent float4 loads in flight
    const float4* h40 = (const float4*)(h + (size_t)node0 * D_FEAT);
    const float4* h41 = (const float4*)(h + (size_t)(node0 + 1) * D_FEAT);
    float4 hv0[4], hv1[4];
    #pragma unroll
    for (int j = 0; j < 4; ++j) hv0[j] = h40[j * 8 + t];
    if (two) {
        #pragma unroll
        for (int j = 0; j < 4; ++j) hv1[j] = h41[j * 8 + t];
    }

    float su0 = 0.f, sv0 = 0.f, su1 = 0.f, sv1 = 0.f;
    #pragma unroll
    for (int j = 0; j < 4; ++j) {
        su0 += hv0[j].x*wu[j].x + hv0[j].y*wu[j].y + hv0[j].z*wu[j].z + hv0[j].w*wu[j].w;
        sv0 += hv0[j].x*wv[j].x + hv0[j].y*wv[j].y + hv0[j].z*wv[j].z + hv0[j].w*wv[j].w;
    }
    if (two) {
        #pragma unroll
        for (int j = 0; j < 4; ++j) {
            su1 += hv1[j].x*wu[j].x + hv1[j].y*wu[j].y + hv1[j].z*wu[j].z + hv1[j].w*wu[j].w;
            sv1 += hv1[j].x*wv[j].x + hv1[j].y*wv[j].y + hv1[j].z*wv[j].z + hv1[j].w*wv[j].w;
        }
    }

    #pragma unroll
    for (int off = 4; off > 0; off >>= 1) {   // xor 4,2,1: stays in 8-lane group
        su0 += __shfl_xor(su0, off, 64);
        sv0 += __shfl_xor(sv0, off, 64);
        su1 += __shfl_xor(su1, off, 64);
        sv1 += __shfl_xor(sv1, off, 64);
    }

    if (t == 0) {
        const float bb = bptr[0];
        if (two) {   // consecutive nodes: one float2 store each for pu, pv
            *(float2*)(pu + node0) = make_float2(su0 + bb, su1 + bb);
            *(float2*)(pv + node0) = make_float2(sv0, sv1);
        } else {
            pu[node0] = su0 + bb;
            pv[node0] = sv0;
        }
    }
}

// K2: 1 edge/thread, 3125 blocks (max TLP). Raw score -> out.
// Per-block min/max partial (one float2 per block, distinct addresses — no atomics).
__global__ __launch_bounds__(256) void score_kernel(
    const int*   __restrict__ src,
    const int*   __restrict__ dst,
    const float* __restrict__ pu,
    const float* __restrict__ pv,
    float*       __restrict__ out,
    float2*      __restrict__ pminmax,
    int n_edges)
{
    const int i = blockIdx.x * blockDim.x + threadIdx.x;
    float vmin =  3.4028235e38f;
    float vmax = -3.4028235e38f;
    if (i < n_edges) {
        const float s = pu[src[i]] + pv[dst[i]];   // pu/pv: 800 KB, L2-resident
        out[i] = s;
        vmin = s;
        vmax = s;
    }
    #pragma unroll
    for (int off = 32; off > 0; off >>= 1) {
        vmin = fminf(vmin, __shfl_xor(vmin, off, 64));
        vmax = fmaxf(vmax, __shfl_xor(vmax, off, 64));
    }
    __shared__ float smin[4], smax[4];
    const int w = threadIdx.x >> 6;
    if ((threadIdx.x & 63) == 0) { smin[w] = vmin; smax[w] = vmax; }
    __syncthreads();
    if (threadIdx.x == 0) {
        const float a = fminf(fminf(smin[0], smin[1]), fminf(smin[2], smin[3]));
        const float m = fmaxf(fmaxf(smax[0], smax[1]), fmaxf(smax[2], smax[3]));
        pminmax[blockIdx.x] = make_float2(a, m);
    }
}

// K3: one 1024-thread block reduces the partial pairs -> g[0]=min, g[1]=max.
__global__ __launch_bounds__(1024) void minmax_reduce_kernel(
    const float2* __restrict__ pminmax,
    float* __restrict__ g,
    int n)
{
    float vmin =  3.4028235e38f;
    float vmax = -3.4028235e38f;
    for (int i = threadIdx.x; i < n; i += 1024) {
        const float2 p = pminmax[i];
        vmin = fminf(vmin, p.x);
        vmax = fmaxf(vmax, p.y);
    }
    #pragma unroll
    for (int off = 32; off > 0; off >>= 1) {
        vmin = fminf(vmin, __shfl_xor(vmin, off, 64));
        vmax = fmaxf(vmax, __shfl_xor(vmax, off, 64));
    }
    __shared__ float smin[16], smax[16];
    const int w = threadIdx.x >> 6;
    if ((threadIdx.x & 63) == 0) { smin[w] = vmin; smax[w] = vmax; }
    __syncthreads();
    if (threadIdx.x == 0) {
        float a = smin[0], m = smax[0];
        #pragma unroll
        for (int k = 1; k < 16; ++k) { a = fminf(a, smin[k]); m = fmaxf(m, smax[k]); }
        g[0] = a;
        g[1] = m;
    }
}

// K4: in-place normalize, float4, 1 vec4/thread (782 blocks).
__global__ __launch_bounds__(256) void norm_kernel(
    float* __restrict__ out,
    const float* __restrict__ g,
    int n4, int n_edges)
{
    const int i = blockIdx.x * blockDim.x + threadIdx.x;
    if (i >= n4) return;
    const float mn  = g[0];
    const float inv = 1.0f / (g[1] - mn);
    float4 v = ((const float4*)out)[i];
    v.x = (v.x - mn) * inv;
    v.y = (v.y - mn) * inv;
    v.z = (v.z - mn) * inv;
    v.w = (v.w - mn) * inv;
    ((float4*)out)[i] = v;
    if (i == n4 - 1) {
        for (int e = n4 * 4; e < n_edges; ++e)
            out[e] = (out[e] - mn) * inv;
    }
}

extern "C" void kernel_launch(void* const* d_in, const int* in_sizes, int n_in,
                              void* d_out, int out_size, void* d_ws, size_t ws_size,
                              hipStream_t stream) {
    const float* h   = (const float*)d_in[0];
    const int*   src = (const int*)d_in[1];
    const int*   dst = (const int*)d_in[2];
    const float* W   = (const float*)d_in[3];
    const float* b   = (const float*)d_in[4];
    float* out = (float*)d_out;

    const int n_nodes = in_sizes[0] / D_FEAT;
    const int n_edges = in_sizes[1];

    const int blk2 = (n_edges + 255) / 256;    // 3125

    // workspace: pu[n_nodes], pv[n_nodes], pminmax[blk2] (float2), g[2]
    float*  ws      = (float*)d_ws;
    float*  pu      = ws;
    float*  pv      = ws + n_nodes;
    float2* pminmax = (float2*)(ws + 2 * n_nodes);
    float*  g       = ws + 2 * n_nodes + 2 * blk2;

    // K1: 64 nodes / block (32 groups x 2 nodes) -> 1563 blocks
    {
        const int blocks = (n_nodes + 63) / 64;
        proj_kernel<<<blocks, 256, 0, stream>>>(h, W, b, pu, pv, n_nodes);
    }
    // K2: 1 edge/thread -> 3125 blocks, per-block partials, no atomics
    score_kernel<<<blk2, 256, 0, stream>>>(src, dst, pu, pv, out, pminmax, n_edges);
    // K3: single-block reduce of partials
    minmax_reduce_kernel<<<1, 1024, 0, stream>>>(pminmax, g, blk2);
    // K4: normalize in place
    {
        const int n4 = n_edges >> 2;           // 200000
        const int blocks = (n4 + 255) / 256;   // 782
        norm_kernel<<<blocks, 256, 0, stream>>>(out, g, n4, n_edges);
    }
}